// Round 2
// baseline (400.466 us; speedup 1.0000x reference)
//
#include <hip/hip_runtime.h>

// Fused binary-sign depthwise conv:
//   out = dwconv(sign(x), w) + dwconv(x, sign(w)), 3x3, stride 1, pad 1
// x: [N=32, C=128, H=112, W=112] fp32, w: [128,1,3,3] fp32, out same shape as x.
// Memory-bound: 205.5 MB in + 205.5 MB out -> ~65us floor at 6.3 TB/s.

#define CH   128
#define HH   112
#define WW   112
#define NW4  28          // 112 / 4 float4s per row
#define PLANE (HH * WW)

__device__ __forceinline__ float fsign(float v) {
    return (v > 0.0f) ? 1.0f : ((v < 0.0f) ? -1.0f : 0.0f);
}

// sign(v) * w without materializing sign(v):
//   v != 0 -> w with sign flipped by signbit(v);  v == 0 -> 0
__device__ __forceinline__ float sign_mul(float v, float w) {
    unsigned int vb = __float_as_uint(v);
    float r = __uint_as_float(__float_as_uint(w) ^ (vb & 0x80000000u));
    return ((vb << 1) == 0u) ? 0.0f : r;   // (vb<<1)==0 catches +0.0 and -0.0
}

__global__ __launch_bounds__(256) void bisign_dwconv_kernel(
    const float* __restrict__ x,
    const float* __restrict__ wt,
    float* __restrict__ out)
{
    const int plane = blockIdx.x;          // n*CH + c
    const int c = plane & (CH - 1);

    const float* __restrict__ xc = x   + (size_t)plane * PLANE;
    float* __restrict__       oc = out + (size_t)plane * PLANE;

    // 9 taps, block-uniform channel -> scalar (SGPR) weights
    float Wv[9], SWv[9];
#pragma unroll
    for (int k = 0; k < 9; ++k) {
        const float wv = wt[c * 9 + k];
        Wv[k]  = wv;
        SWv[k] = fsign(wv);
    }

    for (int idx = threadIdx.x; idx < HH * NW4; idx += 256) {
        const int h   = idx / NW4;
        const int w4  = idx - h * NW4;
        const int col = w4 * 4;

        float acc0 = 0.f, acc1 = 0.f, acc2 = 0.f, acc3 = 0.f;

#pragma unroll
        for (int dr = 0; dr < 3; ++dr) {
            const int r = h + dr - 1;
            float v0, v1, v2, v3, v4, v5;
            if (r >= 0 && r < HH) {
                const float* row = xc + r * WW + col;
                const float4 m = *reinterpret_cast<const float4*>(row);
                v1 = m.x; v2 = m.y; v3 = m.z; v4 = m.w;
                v0 = (w4 > 0)       ? row[-1] : 0.0f;
                v5 = (w4 < NW4 - 1) ? row[4]  : 0.0f;
            } else {
                v0 = v1 = v2 = v3 = v4 = v5 = 0.0f;
            }

            const float w0 = Wv[dr * 3 + 0], w1 = Wv[dr * 3 + 1], w2 = Wv[dr * 3 + 2];
            const float q0 = SWv[dr * 3 + 0], q1 = SWv[dr * 3 + 1], q2 = SWv[dr * 3 + 2];

            // out[p] += sum_j sign(v[p+j])*w[j] + v[p+j]*sign(w[j])
            acc0 += sign_mul(v0, w0) + v0 * q0;
            acc0 += sign_mul(v1, w1) + v1 * q1;
            acc0 += sign_mul(v2, w2) + v2 * q2;

            acc1 += sign_mul(v1, w0) + v1 * q0;
            acc1 += sign_mul(v2, w1) + v2 * q1;
            acc1 += sign_mul(v3, w2) + v3 * q2;

            acc2 += sign_mul(v2, w0) + v2 * q0;
            acc2 += sign_mul(v3, w1) + v3 * q1;
            acc2 += sign_mul(v4, w2) + v4 * q2;

            acc3 += sign_mul(v3, w0) + v3 * q0;
            acc3 += sign_mul(v4, w1) + v4 * q1;
            acc3 += sign_mul(v5, w2) + v5 * q2;
        }

        float4 o;
        o.x = acc0; o.y = acc1; o.z = acc2; o.w = acc3;
        *reinterpret_cast<float4*>(oc + h * WW + col) = o;
    }
}

extern "C" void kernel_launch(void* const* d_in, const int* in_sizes, int n_in,
                              void* d_out, int out_size, void* d_ws, size_t ws_size,
                              hipStream_t stream) {
    const float* x  = (const float*)d_in[0];
    const float* wt = (const float*)d_in[1];
    float* out = (float*)d_out;

    const int N = in_sizes[0] / (CH * PLANE);   // 32
    const int nblocks = N * CH;                 // one block per (n, c) plane

    bisign_dwconv_kernel<<<nblocks, 256, 0, stream>>>(x, wt, out);
}

// Round 6
// 358.414 us; speedup vs baseline: 1.1173x; 1.1173x over previous
//
#include <hip/hip_runtime.h>

// Fused binary-sign depthwise conv:
//   out = dwconv(sign(x), w) + dwconv(x, sign(w)), 3x3, stride 1, pad 1
// x: [N=32, C=128, H=112, W=112] fp32, w: [128,1,3,3] fp32, out same shape.
//
// R2 post-mortem: latency/issue-bound (166us, 1.87 TB/s, VALU 42%). Fix:
// register row-rotation — each thread does a 4-wide x 7-row strip, input rows
// loaded ONCE into a 3-row register ring (3x fewer load instrs / L1 reads),
// sign(x) computed once per element and reused across all 9 taps.
// (R3-R5 were acquisition timeouts; same kernel resubmitted, still unmeasured.)

#define CH    128
#define HH    112
#define WW    112
#define NW4   28            // 112/4 float4 columns
#define PLANE (HH * WW)
#define RPT   7             // output rows per thread
#define NRG   (HH / RPT)    // 16 row-groups
#define NTHR  (NW4 * NRG)   // 448 threads = 7 waves

__device__ __forceinline__ float sgn(float v) {
    // +-1 with v's sign, 0 for +-0:  or(and(v,signbit), 1.0f) + cndmask
    float one = __uint_as_float(0x3f800000u | (__float_as_uint(v) & 0x80000000u));
    return (v == 0.0f) ? 0.0f : one;
}

// Load one input row (6 vals: col-1 .. col+4), zero outside the image.
#define LOADROW(r, V)                                                 \
  {                                                                   \
    const int rr_ = (r);                                              \
    if (rr_ >= 0 && rr_ < HH) {                                       \
      const float* row_ = xc + rr_ * WW + col;                        \
      const float4 m_ = *reinterpret_cast<const float4*>(row_);       \
      V[1] = m_.x; V[2] = m_.y; V[3] = m_.z; V[4] = m_.w;             \
      V[0] = has_l ? row_[-1] : 0.0f;                                 \
      V[5] = has_r ? row_[4]  : 0.0f;                                 \
    } else {                                                          \
      V[0] = V[1] = V[2] = V[3] = V[4] = V[5] = 0.0f;                 \
    }                                                                 \
  }

#define SIGNROW(V, S)                                                 \
  { S[0]=sgn(V[0]); S[1]=sgn(V[1]); S[2]=sgn(V[2]);                   \
    S[3]=sgn(V[3]); S[4]=sgn(V[4]); S[5]=sgn(V[5]); }

// Accumulate one kernel row dr (weights W/Q uniform -> SGPR) into a0..a3.
#define ACCR(V, S, dr)                                                        \
    a0 = fmaf(S[0], W[3*(dr)+0], fmaf(V[0], Q[3*(dr)+0], a0));                \
    a0 = fmaf(S[1], W[3*(dr)+1], fmaf(V[1], Q[3*(dr)+1], a0));                \
    a0 = fmaf(S[2], W[3*(dr)+2], fmaf(V[2], Q[3*(dr)+2], a0));                \
    a1 = fmaf(S[1], W[3*(dr)+0], fmaf(V[1], Q[3*(dr)+0], a1));                \
    a1 = fmaf(S[2], W[3*(dr)+1], fmaf(V[2], Q[3*(dr)+1], a1));                \
    a1 = fmaf(S[3], W[3*(dr)+2], fmaf(V[3], Q[3*(dr)+2], a1));                \
    a2 = fmaf(S[2], W[3*(dr)+0], fmaf(V[2], Q[3*(dr)+0], a2));                \
    a2 = fmaf(S[3], W[3*(dr)+1], fmaf(V[3], Q[3*(dr)+1], a2));                \
    a2 = fmaf(S[4], W[3*(dr)+2], fmaf(V[4], Q[3*(dr)+2], a2));                \
    a3 = fmaf(S[3], W[3*(dr)+0], fmaf(V[3], Q[3*(dr)+0], a3));                \
    a3 = fmaf(S[4], W[3*(dr)+1], fmaf(V[4], Q[3*(dr)+1], a3));                \
    a3 = fmaf(S[5], W[3*(dr)+2], fmaf(V[5], Q[3*(dr)+2], a3));

// One output row: load the new bottom row into (VB,SB), reuse (VT,VM).
#define STEP(i, VT, ST, VM, SM, VB, SB)                               \
  {                                                                   \
    LOADROW(rbase + (i) + 1, VB);                                     \
    SIGNROW(VB, SB);                                                  \
    float a0 = 0.f, a1 = 0.f, a2 = 0.f, a3 = 0.f;                     \
    ACCR(VT, ST, 0);                                                  \
    ACCR(VM, SM, 1);                                                  \
    ACCR(VB, SB, 2);                                                  \
    float4 o_; o_.x = a0; o_.y = a1; o_.z = a2; o_.w = a3;            \
    *reinterpret_cast<float4*>(oc + (rbase + (i)) * WW + col) = o_;   \
  }

__global__ __launch_bounds__(NTHR) void bisign_dwconv_kernel(
    const float* __restrict__ x,
    const float* __restrict__ wt,
    float* __restrict__ out)
{
    const int plane = blockIdx.x;              // n*CH + c
    const int c = plane & (CH - 1);

    const float* __restrict__ xc = x   + (size_t)plane * PLANE;
    float* __restrict__       oc = out + (size_t)plane * PLANE;

    // 9 taps, block-uniform channel -> scalar weights (SGPR)
    float W[9], Q[9];
#pragma unroll
    for (int k = 0; k < 9; ++k) {
        const float wv = wt[c * 9 + k];
        W[k] = wv;
        Q[k] = sgn(wv);
    }

    const int tid   = threadIdx.x;
    const int col4  = tid % NW4;               // 0..27
    const int rg    = tid / NW4;               // 0..15
    const int col   = col4 * 4;
    const int rbase = rg * RPT;

    const bool has_l = (col4 > 0);
    const bool has_r = (col4 < NW4 - 1);

    // 3-row register ring: values + signs (all statically indexed)
    float V0[6], V1[6], V2[6], S0[6], S1[6], S2[6];

    LOADROW(rbase - 1, V0); SIGNROW(V0, S0);
    LOADROW(rbase,     V1); SIGNROW(V1, S1);

    STEP(0, V0, S0, V1, S1, V2, S2);
    STEP(1, V1, S1, V2, S2, V0, S0);
    STEP(2, V2, S2, V0, S0, V1, S1);
    STEP(3, V0, S0, V1, S1, V2, S2);
    STEP(4, V1, S1, V2, S2, V0, S0);
    STEP(5, V2, S2, V0, S0, V1, S1);
    STEP(6, V0, S0, V1, S1, V2, S2);
}

extern "C" void kernel_launch(void* const* d_in, const int* in_sizes, int n_in,
                              void* d_out, int out_size, void* d_ws, size_t ws_size,
                              hipStream_t stream) {
    const float* x  = (const float*)d_in[0];
    const float* wt = (const float*)d_in[1];
    float* out = (float*)d_out;

    const int N = in_sizes[0] / (CH * PLANE);   // 32
    const int nblocks = N * CH;                 // one block per (n, c) plane

    bisign_dwconv_kernel<<<nblocks, NTHR, 0, stream>>>(x, wt, out);
}